// Round 3
// baseline (417.494 us; speedup 1.0000x reference)
//
#include <hip/hip_runtime.h>
#include <stdint.h>

#define EPS 1e-20f
#define H_ 192
#define W_ 192
#define HW_ 36864
#define CH4 128
#define OUTELEMS 18874368  // 4*128*36864 elements per output tensor

typedef __attribute__((ext_vector_type(8))) short bf16x8;
typedef __attribute__((ext_vector_type(4))) float f32x4;

// ---- bf16 pack helpers (RNE) for intermediates ----
__device__ __forceinline__ unsigned short f2bf(float f) {
  unsigned u = __float_as_uint(f);
  return (unsigned short)((u + 0x7fffu + ((u >> 16) & 1u)) >> 16);
}
__device__ __forceinline__ float bflo(unsigned v) { return __uint_as_float(v << 16); }
__device__ __forceinline__ float bfhi(unsigned v) { return __uint_as_float(v & 0xffff0000u); }

// ---- k0: pack channel_weight into MFMA A-fragments (hi/lo bf16 split) + sums ----
// AW layout: n = ((ot*4 + kb)*64 + lane)*8 + t
//   lane = r + 16*g  ->  A row (output) o = ot*16 + r ; k-elem ch = kb*32 + g*8 + t
__global__ void __launch_bounds__(256) k0_prep(const float* __restrict__ cw,
                                               const float* __restrict__ sw,
                                               unsigned short* __restrict__ AWhi,
                                               unsigned short* __restrict__ AWlo,
                                               float* __restrict__ sums) {
  int tid = threadIdx.x;
  if (blockIdx.x < 64) {
    int n = blockIdx.x * 256 + tid;   // 0..16383
    int t = n & 7;
    int l = (n >> 3) & 63;
    int kb = (n >> 9) & 3;
    int ot = n >> 11;
    int o = ot * 16 + (l & 15);
    int i = kb * 32 + (l >> 4) * 8 + t;
    float wv = cw[o * 128 + i];
    unsigned short hi = f2bf(wv);
    float hif = bflo((unsigned)hi);
    unsigned short lo = f2bf(wv - hif);
    AWhi[n] = hi;
    AWlo[n] = lo;
  } else {
    __shared__ float red[256];
    float s = 0.f;
    for (int k = tid; k < 16384; k += 256) s += cw[k];
    red[tid] = s; __syncthreads();
    for (int off = 128; off > 0; off >>= 1) {
      if (tid < off) red[tid] += red[tid + off];
      __syncthreads();
    }
    if (tid == 0) sums[0] = red[0];
    __syncthreads();
    s = 0.f;
    for (int k = tid; k < 3200; k += 256) s += sw[k];
    red[tid] = s; __syncthreads();
    for (int off = 128; off > 0; off >>= 1) {
      if (tid < off) red[tid] += red[tid + off];
      __syncthreads();
    }
    if (tid == 0) sums[1] = red[0];
  }
}

// ---- k1: stencil stage -> packed (X=ce1*e1, Y=ce1) bf16x2, planar (B,128,H,W) ----
// v3: keys computed once per staged position (IEEE div kept for exact argmax).
//     Scan winners held in REGISTERS across a barrier, then written as value
//     maps ALIASED over the dead stage buffers (LDS 20736 B -> 7 blocks/CU).
//     Phase 3: 4 consecutive px/thread -> float4/uint4 global I/O, lane-
//     consecutive (stride-35, ~2-way) map reads. No data-dependent gathers.
__global__ void __launch_bounds__(256) k1_stage1(
    const float* __restrict__ d, const float* __restrict__ cd,
    const float* __restrict__ e, const float* __restrict__ ce,
    const float* __restrict__ wprop, const float* __restrict__ wsd,
    unsigned* __restrict__ XY) {
  const int tid = threadIdx.x;
  const int tile = blockIdx.x;  // 36 tiles of 32x32
  const int th0 = (tile / 6) * 32, tw0 = (tile % 6) * 32;
  const int bc = blockIdx.y;  // b*32+c
  const int b = bc >> 5, c = bc & 31;

  // Phase 1/2 layout: dpL=S, cdpL=S+1296, kxL=S+2592, knL=S+3888  (36x36 grids)
  // Phase 3 layout (aliased after barrier): DMN=S, DMX=S+1190, CMN=S+2380,
  //   CMX=S+3570 (34x34 grids at stride 35; 4760 <= 5184 floats)
  __shared__ float S[5184];
  float* dpL = S;
  float* cdpL = S + 1296;
  float* kxL = S + 2592;
  float* knL = S + 3888;

  const float* dB = d + bc * HW_;
  const float* cdB = cd + bc * HW_;
  for (int idx = tid; idx < 1296; idx += 256) {
    int ly = idx / 36, lx = idx % 36;
    int gy = th0 + ly - 2, gx = tw0 + lx - 2;  // original-image coords
    float dv = 0.f, cv = 0.f;
    if (gy >= 0 && gy < H_ && gx >= 0 && gx < W_) {
      dv = dB[gy * W_ + gx];
      cv = cdB[gy * W_ + gx];
    }
    dpL[idx] = dv; cdpL[idx] = cv;
    // key in-bounds iff inside the reference's zero-PADDED grid
    bool inb = (gy >= -1) & (gy <= H_) & (gx >= -1) & (gx <= W_);
    kxL[idx] = inb ? dv * cv : -1.f;          // -1 sentinel (< all real keys >= 0)
    knL[idx] = inb ? cv / (dv + EPS) : -1.f;  // IEEE div: exact argmax vs reference
  }
  __syncthreads();

  // Phase 2: scan in registers; winner values survive the barrier in regs.
  float rdmn[5], rdmx[5], rcmn[5], rcmx[5];
#pragma unroll
  for (int i = 0; i < 5; ++i) {
    int idx = i * 256 + tid;
    if (idx < 1156) {
      int ly = idx / 34, lx = idx % 34;
      int base = ly * 36 + lx;
      float bkx = -1.f, bkn = -1.f;
      int ox = base + 37, on = base + 37;
#pragma unroll
      for (int di = 0; di < 3; ++di) {
#pragma unroll
        for (int dj = 0; dj < 3; ++dj) {
          int o = base + di * 36 + dj;
          float kx = kxL[o], kn = knL[o];
          if (kx > bkx) { bkx = kx; ox = o; }  // strict > = numpy argmax first-wins
          if (kn > bkn) { bkn = kn; on = o; }
        }
      }
      rdmx[i] = dpL[ox]; rcmx[i] = cdpL[ox];
      rdmn[i] = dpL[on]; rcmn[i] = cdpL[on];
    } else {
      rdmx[i] = 0.f; rcmx[i] = 0.f; rdmn[i] = 0.f; rcmn[i] = 0.f;
    }
  }
  __syncthreads();  // all phase-2 reads done; safe to overwrite S

  float* DMN = S;
  float* DMX = S + 1190;
  float* CMN = S + 2380;
  float* CMX = S + 3570;
#pragma unroll
  for (int i = 0; i < 5; ++i) {
    int idx = i * 256 + tid;
    if (idx < 1156) {
      int ly = idx / 34, lx = idx % 34;
      int m = ly * 35 + lx;  // stride 35: spreads banks for phase-3 reads
      DMN[m] = rdmn[i]; DMX[m] = rdmx[i];
      CMN[m] = rcmn[i]; CMX[m] = rcmx[i];
    }
  }
  __syncthreads();

  const float wp = wprop[c];
  const float iwp1 = __builtin_amdgcn_rcpf(wp + 1.0f);
  float wq[8];
#pragma unroll
  for (int t = 0; t < 8; ++t) wq[t] = wsd[c * 8 + t];  // [ord*4 + pair]

  const int offy[4] = {-1, -1, -1, 0};
  const int offx[4] = {-1, 0, 1, 1};

  // Phase 3: 4 consecutive pixels per thread -> float4 loads / uint4 stores.
  const int ly = tid >> 3, lx4 = (tid & 7) << 2;
  const int hh = th0 + ly, ww0 = tw0 + lx4;
#pragma unroll
  for (int p = 0; p < 4; ++p) {
    int n1 = (ly + offy[p] + 1) * 35 + (lx4 + offx[p] + 1);
    int n2 = (ly - offy[p] + 1) * 35 + (lx4 - offx[p] + 1);
    int ei = (bc * 4 + p) * HW_ + hh * W_ + ww0;
    float4 ev4 = *reinterpret_cast<const float4*>(&e[ei]);
    float4 cev4 = *reinterpret_cast<const float4*>(&ce[ei]);
    const float* evp = &ev4.x;
    const float* cevp = &cev4.x;
    unsigned ow[4];
#pragma unroll
    for (int k = 0; k < 4; ++k) {
      float dmn1 = DMN[n1 + k], cmn1 = CMN[n1 + k];
      float dmx1 = DMX[n1 + k], cmx1 = CMX[n1 + k];
      float dmn2 = DMN[n2 + k], cmn2 = CMN[n2 + k];
      float dmx2 = DMX[n2 + k], cmx2 = CMX[n2 + k];
      // continuous path: fast rcp / native log2+exp2 (error ~1ulp << bf16 quantum)
      float r0 = dmn1 * __builtin_amdgcn_rcpf(dmx2 + EPS);
      float r1 = dmx1 * __builtin_amdgcn_rcpf(dmn2 + EPS);
      float cr0 = cmn1 * cmx2;
      float cr1 = cmx1 * cmn2;
      float x0 = fminf(fmaxf(r0, EPS), 1.0f);
      float x1 = fminf(fmaxf(r1, EPS), 1.0f);
      float dr0 = __builtin_amdgcn_exp2f(wq[p] * __builtin_amdgcn_logf(x0));
      float dr1 = __builtin_amdgcn_exp2f(wq[4 + p] * __builtin_amdgcn_logf(x1));
      // select ord with larger cr/dr; cross-multiplied (all >=0), tie -> ord0.
      float ef, cf;
      if (cr1 * dr0 > cr0 * dr1) { ef = dr1; cf = cr1; } else { ef = dr0; cf = cr0; }
      float ev = evp[k], cev = cevp[k];
      float dn = wp * cev + cf;
      float e1 = (wp * cev * ev + cf * ef) * __builtin_amdgcn_rcpf(dn + EPS);
      float ce1 = dn * iwp1;
      ow[k] = (unsigned)f2bf(ce1 * e1) | ((unsigned)f2bf(ce1) << 16);
    }
    unsigned* xo = &XY[(b * CH4 + c * 4 + p) * HW_ + hh * W_ + ww0];
    *reinterpret_cast<uint4*>(xo) = make_uint4(ow[0], ow[1], ow[2], ow[3]);
  }
}

// ---- k2: per-pixel channel mix as bf16 MFMA GEMM pair ----
// Block: 256 thr = 4 waves; tile = 64 pixels x 128 outputs; K = 128 channels.
// LDS stage [128 ch][stride 66 u32] of packed XY; each wave owns 16 pixels.
__global__ void __launch_bounds__(256) k2_mix(const unsigned* __restrict__ XY,
                                              const unsigned short* __restrict__ AWhi,
                                              const unsigned short* __restrict__ AWlo,
                                              const float* __restrict__ sums,
                                              unsigned* __restrict__ PQ) {
  __shared__ unsigned L[128 * 66];  // stride 66: 2-way bank alias on frag reads (free)
  const int tid = threadIdx.x;
  const int blk = blockIdx.x;           // 2304 blocks
  const int b = blk / 576;
  const int hw0 = (blk % 576) * 64;
  const unsigned* xp = XY + (size_t)(b * CH4) * HW_ + hw0;

  // stage: 128 ch x 64 px u32, dwordx4 global loads, b64 LDS writes (8B aligned)
#pragma unroll
  for (int j = 0; j < 8; ++j) {
    int v = j * 256 + tid;      // 0..2047 vec4-index
    int ch = v >> 4;            // 16 vec4 per channel row
    int po = (v & 15) * 4;
    uint4 val = *reinterpret_cast<const uint4*>(xp + (size_t)ch * HW_ + po);
    unsigned* dst = &L[ch * 66 + po];
    *reinterpret_cast<uint2*>(dst) = make_uint2(val.x, val.y);
    *reinterpret_cast<uint2*>(dst + 2) = make_uint2(val.z, val.w);
  }
  __syncthreads();

  const int lane = tid & 63;
  const int w = tid >> 6;       // wave id -> pixel quarter
  const int c = lane & 15;      // MFMA N-col = pixel
  const int g = lane >> 4;      // k-group
  const int pbase = w * 16 + c;

  // B fragments: x (nom) and y (den), 4 K-blocks of 32
  bf16x8 xf[4], yf[4];
#pragma unroll
  for (int kb = 0; kb < 4; ++kb) {
    unsigned vv[8];
    const unsigned* base = &L[(kb * 32 + g * 8) * 66 + pbase];
#pragma unroll
    for (int t = 0; t < 8; ++t) vv[t] = base[t * 66];
    union { bf16x8 v; unsigned u[4]; } ux, uy;
#pragma unroll
    for (int p = 0; p < 4; ++p) {
      ux.u[p] = (vv[2 * p] & 0xffffu) | (vv[2 * p + 1] << 16);
      uy.u[p] = (vv[2 * p] >> 16) | (vv[2 * p + 1] & 0xffff0000u);
    }
    xf[kb] = ux.v;
    yf[kb] = uy.v;
  }

  const float inv = 1.0f / (sums[0] + EPS);
  unsigned* qp = PQ + (size_t)(b * CH4) * HW_ + hw0;

#pragma unroll 2
  for (int ot = 0; ot < 8; ++ot) {
    f32x4 accn = {0.f, 0.f, 0.f, 0.f};
    f32x4 accd = {0.f, 0.f, 0.f, 0.f};
#pragma unroll
    for (int kb = 0; kb < 4; ++kb) {
      int an = ((ot * 4 + kb) * 64 + lane) * 8;
      bf16x8 ahi = *reinterpret_cast<const bf16x8*>(AWhi + an);
      bf16x8 alo = *reinterpret_cast<const bf16x8*>(AWlo + an);
      accn = __builtin_amdgcn_mfma_f32_16x16x32_bf16(ahi, xf[kb], accn, 0, 0, 0);
      accn = __builtin_amdgcn_mfma_f32_16x16x32_bf16(alo, xf[kb], accn, 0, 0, 0);
      accd = __builtin_amdgcn_mfma_f32_16x16x32_bf16(ahi, yf[kb], accd, 0, 0, 0);
      accd = __builtin_amdgcn_mfma_f32_16x16x32_bf16(alo, yf[kb], accd, 0, 0, 0);
    }
    // C/D: col = lane&15 (pixel), row = g*4 + j (output within o-tile) [m89-verified]
#pragma unroll
    for (int j = 0; j < 4; ++j) {
      int o = ot * 16 + g * 4 + j;
      qp[(size_t)o * HW_ + w * 16 + c] =
          (unsigned)f2bf(accn[j] * inv) | ((unsigned)f2bf(accd[j] * inv) << 16);
    }
  }
}

// ---- k3: depthwise 5x5 conv on P,Q + final ratios -> FP32 outputs ----
__global__ void __launch_bounds__(256) k3_conv(const unsigned* __restrict__ PQ,
                                               const float* __restrict__ sw,
                                               const float* __restrict__ sums,
                                               float* __restrict__ out0,
                                               float* __restrict__ out1) {
  int t = blockIdx.x;
  int tile = t % 36;
  int chb = t / 36;  // b*128+ch
  int ch = chb & 127;
  int th0 = (tile / 6) * 32, tw0 = (tile % 6) * 32;
  __shared__ float Pt[1296], Qt[1296];
  const unsigned* src = PQ + chb * HW_;
  int tid = threadIdx.x;
  for (int idx = tid; idx < 1296; idx += 256) {
    int ly = idx / 36, lx = idx % 36;
    int gy = th0 + ly - 2, gx = tw0 + lx - 2;
    unsigned v = 0;
    if (gy >= 0 && gy < H_ && gx >= 0 && gx < W_) v = src[gy * W_ + gx];
    Pt[idx] = bflo(v); Qt[idx] = bfhi(v);
  }
  __syncthreads();
  float wr[25];
#pragma unroll
  for (int k = 0; k < 25; ++k) wr[k] = sw[ch * 25 + k];
  float isw = 1.0f / (sums[1] + EPS);
  int x = tid & 31, yg = tid >> 5;  // 32 cols x 8 row-groups (4 rows each)
  float an[4] = {0, 0, 0, 0}, ad[4] = {0, 0, 0, 0};
#pragma unroll
  for (int rr = 0; rr < 8; ++rr) {
    int Lr = yg * 4 + rr;
    float pv[5], qv[5];
#pragma unroll
    for (int c5 = 0; c5 < 5; ++c5) {
      pv[c5] = Pt[Lr * 36 + x + c5];
      qv[c5] = Qt[Lr * 36 + x + c5];
    }
#pragma unroll
    for (int k = 0; k < 4; ++k) {
      int ky = rr - k;
      if (ky >= 0 && ky <= 4) {
#pragma unroll
        for (int c5 = 0; c5 < 5; ++c5) {
          an[k] += pv[c5] * wr[ky * 5 + c5];
          ad[k] += qv[c5] * wr[ky * 5 + c5];
        }
      }
    }
  }
#pragma unroll
  for (int k = 0; k < 4; ++k) {
    int hh = th0 + yg * 4 + k;
    int oi = chb * HW_ + hh * W_ + tw0 + x;
    out0[oi] = an[k] / (ad[k] + EPS);
    out1[oi] = ad[k] * isw;
  }
}

extern "C" void kernel_launch(void* const* d_in, const int* in_sizes, int n_in,
                              void* d_out, int out_size, void* d_ws, size_t ws_size,
                              hipStream_t stream) {
  const float* d = (const float*)d_in[0];
  const float* cd = (const float*)d_in[1];
  const float* e = (const float*)d_in[2];
  const float* ce = (const float*)d_in[3];
  const float* wprop = (const float*)d_in[4];
  const float* wsd = (const float*)d_in[5];
  const float* cw = (const float*)d_in[6];
  const float* sw = (const float*)d_in[7];

  // ws layout (75.6 MB): sums(64 f32) | AWhi(16384 bf16) | AWlo(16384 bf16) | PQ(18874368 u32)
  // XY (bf16x2, 75.5 MB) staged in UPPER HALF of d_out; k2 consumes it before k3 writes.
  float* wsf = (float*)d_ws;
  float* sums = wsf;
  unsigned short* AWhi = (unsigned short*)(wsf + 64);
  unsigned short* AWlo = AWhi + 16384;
  unsigned* PQ = (unsigned*)(wsf + 64 + 16384);
  float* out0 = (float*)d_out;
  float* out1 = out0 + OUTELEMS;
  unsigned* XY = (unsigned*)(out0 + OUTELEMS);

  hipLaunchKernelGGL(k0_prep, dim3(65), dim3(256), 0, stream, cw, sw, AWhi, AWlo, sums);
  hipLaunchKernelGGL(k1_stage1, dim3(36, 128), dim3(256), 0, stream, d, cd, e, ce,
                     wprop, wsd, XY);
  hipLaunchKernelGGL(k2_mix, dim3(2304), dim3(256), 0, stream, XY, AWhi, AWlo, sums, PQ);
  hipLaunchKernelGGL(k3_conv, dim3(18432), dim3(256), 0, stream, PQ, sw, sums, out0,
                     out1);
}

// Round 4
// 407.721 us; speedup vs baseline: 1.0240x; 1.0240x over previous
//
#include <hip/hip_runtime.h>
#include <stdint.h>

#define EPS 1e-20f
#define H_ 192
#define W_ 192
#define HW_ 36864
#define CH4 128
#define OUTELEMS 18874368  // 4*128*36864 elements per output tensor

typedef __attribute__((ext_vector_type(8))) short bf16x8;
typedef __attribute__((ext_vector_type(4))) float f32x4;

// ---- bf16 pack helpers (RNE) for intermediates ----
__device__ __forceinline__ unsigned short f2bf(float f) {
  unsigned u = __float_as_uint(f);
  return (unsigned short)((u + 0x7fffu + ((u >> 16) & 1u)) >> 16);
}
__device__ __forceinline__ float bflo(unsigned v) { return __uint_as_float(v << 16); }
__device__ __forceinline__ float bfhi(unsigned v) { return __uint_as_float(v & 0xffff0000u); }

// ---- k0: pack channel_weight into MFMA A-fragments (hi/lo bf16 split) + sums ----
// AW layout: n = ((ot*4 + kb)*64 + lane)*8 + t
//   lane = r + 16*g  ->  A row (output) o = ot*16 + r ; k-elem ch = kb*32 + g*8 + t
__global__ void __launch_bounds__(256) k0_prep(const float* __restrict__ cw,
                                               const float* __restrict__ sw,
                                               unsigned short* __restrict__ AWhi,
                                               unsigned short* __restrict__ AWlo,
                                               float* __restrict__ sums) {
  int tid = threadIdx.x;
  if (blockIdx.x < 64) {
    int n = blockIdx.x * 256 + tid;   // 0..16383
    int t = n & 7;
    int l = (n >> 3) & 63;
    int kb = (n >> 9) & 3;
    int ot = n >> 11;
    int o = ot * 16 + (l & 15);
    int i = kb * 32 + (l >> 4) * 8 + t;
    float wv = cw[o * 128 + i];
    unsigned short hi = f2bf(wv);
    float hif = bflo((unsigned)hi);
    unsigned short lo = f2bf(wv - hif);
    AWhi[n] = hi;
    AWlo[n] = lo;
  } else {
    __shared__ float red[256];
    float s = 0.f;
    for (int k = tid; k < 16384; k += 256) s += cw[k];
    red[tid] = s; __syncthreads();
    for (int off = 128; off > 0; off >>= 1) {
      if (tid < off) red[tid] += red[tid + off];
      __syncthreads();
    }
    if (tid == 0) sums[0] = red[0];
    __syncthreads();
    s = 0.f;
    for (int k = tid; k < 3200; k += 256) s += sw[k];
    red[tid] = s; __syncthreads();
    for (int off = 128; off > 0; off >>= 1) {
      if (tid < off) red[tid] += red[tid + off];
      __syncthreads();
    }
    if (tid == 0) sums[1] = red[0];
  }
}

// ---- k1: stencil stage -> packed (X=ce1*e1, Y=ce1) bf16x2, planar (B,128,H,W) ----
// v4: phase-1/2 keys+values packed as float2 (b64 LDS ops: 22->11 reads/position
//     in the scan, 4->2 writes in stage); phase-3 e/ce float4 loads hoisted ahead
//     of the map math (latency hidden under ~500 VALU ops). Maps scalar stride-35
//     (2-way alias, free). Same numerics as v3.
__global__ void __launch_bounds__(256) k1_stage1(
    const float* __restrict__ d, const float* __restrict__ cd,
    const float* __restrict__ e, const float* __restrict__ ce,
    const float* __restrict__ wprop, const float* __restrict__ wsd,
    unsigned* __restrict__ XY) {
  const int tid = threadIdx.x;
  const int tile = blockIdx.x;  // 36 tiles of 32x32
  const int th0 = (tile / 6) * 32, tw0 = (tile % 6) * 32;
  const int bc = blockIdx.y;  // b*32+c
  const int b = bc >> 5, c = bc & 31;

  // Phase 1/2: K2[idx]=(kx,kn), V2[idx]=(d,cd) on 36x36 grid (float2, b64 ops).
  // Phase 3 (aliased after barrier): 4 scalar maps on 34x34 grid, stride 35.
  __shared__ float2 S2[2592];  // 20736 B -> 7 blocks/CU
  float2* K2 = S2;
  float2* V2 = S2 + 1296;
  float* S = (float*)S2;

  const float* dB = d + bc * HW_;
  const float* cdB = cd + bc * HW_;
  for (int idx = tid; idx < 1296; idx += 256) {
    int ly = idx / 36, lx = idx % 36;
    int gy = th0 + ly - 2, gx = tw0 + lx - 2;  // original-image coords
    float dv = 0.f, cv = 0.f;
    if (gy >= 0 && gy < H_ && gx >= 0 && gx < W_) {
      dv = dB[gy * W_ + gx];
      cv = cdB[gy * W_ + gx];
    }
    // key in-bounds iff inside the reference's zero-PADDED grid
    bool inb = (gy >= -1) & (gy <= H_) & (gx >= -1) & (gx <= W_);
    float kx = inb ? dv * cv : -1.f;          // -1 sentinel (< all real keys >= 0)
    float kn = inb ? cv / (dv + EPS) : -1.f;  // IEEE div: exact argmax vs reference
    K2[idx] = make_float2(kx, kn);
    V2[idx] = make_float2(dv, cv);
  }
  __syncthreads();

  // Phase 2: scan in registers; winner values survive the barrier in regs.
  float rdmn[5], rdmx[5], rcmn[5], rcmx[5];
#pragma unroll
  for (int i = 0; i < 5; ++i) {
    int idx = i * 256 + tid;
    if (idx < 1156) {
      int ly = idx / 34, lx = idx % 34;
      int base = ly * 36 + lx;
      float bkx = -1.f, bkn = -1.f;
      int ox = base + 37, on = base + 37;
#pragma unroll
      for (int di = 0; di < 3; ++di) {
#pragma unroll
        for (int dj = 0; dj < 3; ++dj) {
          int o = base + di * 36 + dj;
          float2 kk = K2[o];  // one b64 read per neighbor
          if (kk.x > bkx) { bkx = kk.x; ox = o; }  // strict > = argmax first-wins
          if (kk.y > bkn) { bkn = kk.y; on = o; }
        }
      }
      float2 vx = V2[ox], vn = V2[on];  // two b64 gathers
      rdmx[i] = vx.x; rcmx[i] = vx.y;
      rdmn[i] = vn.x; rcmn[i] = vn.y;
    } else {
      rdmx[i] = 0.f; rcmx[i] = 0.f; rdmn[i] = 0.f; rcmn[i] = 0.f;
    }
  }
  __syncthreads();  // all phase-2 reads done; safe to overwrite S

  float* DMN = S;
  float* DMX = S + 1190;
  float* CMN = S + 2380;
  float* CMX = S + 3570;
#pragma unroll
  for (int i = 0; i < 5; ++i) {
    int idx = i * 256 + tid;
    if (idx < 1156) {
      int ly = idx / 34, lx = idx % 34;
      int m = ly * 35 + lx;  // stride 35: spreads banks for phase-3 reads
      DMN[m] = rdmn[i]; DMX[m] = rdmx[i];
      CMN[m] = rcmn[i]; CMX[m] = rcmx[i];
    }
  }
  __syncthreads();

  const float wp = wprop[c];
  const float iwp1 = __builtin_amdgcn_rcpf(wp + 1.0f);
  float wq[8];
#pragma unroll
  for (int t = 0; t < 8; ++t) wq[t] = wsd[c * 8 + t];  // [ord*4 + pair]

  const int offy[4] = {-1, -1, -1, 0};
  const int offx[4] = {-1, 0, 1, 1};

  // Phase 3: 4 consecutive pixels per thread; all e/ce loads issued up front.
  const int ly = tid >> 3, lx4 = (tid & 7) << 2;
  const int hh = th0 + ly, ww0 = tw0 + lx4;
  float4 ev4[4], cev4[4];
#pragma unroll
  for (int p = 0; p < 4; ++p) {
    int ei = (bc * 4 + p) * HW_ + hh * W_ + ww0;
    ev4[p] = *reinterpret_cast<const float4*>(&e[ei]);
    cev4[p] = *reinterpret_cast<const float4*>(&ce[ei]);
  }
#pragma unroll
  for (int p = 0; p < 4; ++p) {
    int n1 = (ly + offy[p] + 1) * 35 + (lx4 + offx[p] + 1);
    int n2 = (ly - offy[p] + 1) * 35 + (lx4 - offx[p] + 1);
    const float* evp = &ev4[p].x;
    const float* cevp = &cev4[p].x;
    unsigned ow[4];
#pragma unroll
    for (int k = 0; k < 4; ++k) {
      float dmn1 = DMN[n1 + k], cmn1 = CMN[n1 + k];
      float dmx1 = DMX[n1 + k], cmx1 = CMX[n1 + k];
      float dmn2 = DMN[n2 + k], cmn2 = CMN[n2 + k];
      float dmx2 = DMX[n2 + k], cmx2 = CMX[n2 + k];
      // continuous path: fast rcp / native log2+exp2 (error ~1ulp << bf16 quantum)
      float r0 = dmn1 * __builtin_amdgcn_rcpf(dmx2 + EPS);
      float r1 = dmx1 * __builtin_amdgcn_rcpf(dmn2 + EPS);
      float cr0 = cmn1 * cmx2;
      float cr1 = cmx1 * cmn2;
      float x0 = fminf(fmaxf(r0, EPS), 1.0f);
      float x1 = fminf(fmaxf(r1, EPS), 1.0f);
      float dr0 = __builtin_amdgcn_exp2f(wq[p] * __builtin_amdgcn_logf(x0));
      float dr1 = __builtin_amdgcn_exp2f(wq[4 + p] * __builtin_amdgcn_logf(x1));
      // select ord with larger cr/dr; cross-multiplied (all >=0), tie -> ord0.
      float ef, cf;
      if (cr1 * dr0 > cr0 * dr1) { ef = dr1; cf = cr1; } else { ef = dr0; cf = cr0; }
      float ev = evp[k], cev = cevp[k];
      float dn = wp * cev + cf;
      float e1 = (wp * cev * ev + cf * ef) * __builtin_amdgcn_rcpf(dn + EPS);
      float ce1 = dn * iwp1;
      ow[k] = (unsigned)f2bf(ce1 * e1) | ((unsigned)f2bf(ce1) << 16);
    }
    unsigned* xo = &XY[(b * CH4 + c * 4 + p) * HW_ + hh * W_ + ww0];
    *reinterpret_cast<uint4*>(xo) = make_uint4(ow[0], ow[1], ow[2], ow[3]);
  }
}

// ---- k2: per-pixel channel mix as bf16 MFMA GEMM pair ----
// v2: NO LDS stage. Each fragment element is consumed by exactly one lane
//     (16 consecutive px per 16-lane group, one channel each), so the B-frags
//     load DIRECTLY global->VGPR: 64B-coalesced segments, zero barriers,
//     LDS=0 -> occupancy cap 100%.
__global__ void __launch_bounds__(256) k2_mix(const unsigned* __restrict__ XY,
                                              const unsigned short* __restrict__ AWhi,
                                              const unsigned short* __restrict__ AWlo,
                                              const float* __restrict__ sums,
                                              unsigned* __restrict__ PQ) {
  const int tid = threadIdx.x;
  const int blk = blockIdx.x;           // 2304 blocks
  const int b = blk / 576;
  const int hw0 = (blk % 576) * 64;

  const int lane = tid & 63;
  const int w = tid >> 6;       // wave id -> pixel quarter
  const int c = lane & 15;      // MFMA N-col = pixel
  const int g = lane >> 4;      // k-group
  const int px = hw0 + w * 16 + c;
  const unsigned* xp = XY + (size_t)(b * CH4) * HW_ + px;

  // B fragments: x (nom) and y (den), 4 K-blocks of 32; lane reads its own
  // (channel, pixel) element once -> no reuse -> no staging needed.
  bf16x8 xf[4], yf[4];
#pragma unroll
  for (int kb = 0; kb < 4; ++kb) {
    unsigned vv[8];
#pragma unroll
    for (int t = 0; t < 8; ++t) vv[t] = xp[(size_t)(kb * 32 + g * 8 + t) * HW_];
    union { bf16x8 v; unsigned u[4]; } ux, uy;
#pragma unroll
    for (int p = 0; p < 4; ++p) {
      ux.u[p] = (vv[2 * p] & 0xffffu) | (vv[2 * p + 1] << 16);
      uy.u[p] = (vv[2 * p] >> 16) | (vv[2 * p + 1] & 0xffff0000u);
    }
    xf[kb] = ux.v;
    yf[kb] = uy.v;
  }

  const float inv = 1.0f / (sums[0] + EPS);
  unsigned* qp = PQ + (size_t)(b * CH4) * HW_ + px;

#pragma unroll 2
  for (int ot = 0; ot < 8; ++ot) {
    f32x4 accn = {0.f, 0.f, 0.f, 0.f};
    f32x4 accd = {0.f, 0.f, 0.f, 0.f};
#pragma unroll
    for (int kb = 0; kb < 4; ++kb) {
      int an = ((ot * 4 + kb) * 64 + lane) * 8;
      bf16x8 ahi = *reinterpret_cast<const bf16x8*>(AWhi + an);
      bf16x8 alo = *reinterpret_cast<const bf16x8*>(AWlo + an);
      accn = __builtin_amdgcn_mfma_f32_16x16x32_bf16(ahi, xf[kb], accn, 0, 0, 0);
      accn = __builtin_amdgcn_mfma_f32_16x16x32_bf16(alo, xf[kb], accn, 0, 0, 0);
      accd = __builtin_amdgcn_mfma_f32_16x16x32_bf16(ahi, yf[kb], accd, 0, 0, 0);
      accd = __builtin_amdgcn_mfma_f32_16x16x32_bf16(alo, yf[kb], accd, 0, 0, 0);
    }
    // C/D: col = lane&15 (pixel), row = g*4 + j (output within o-tile) [m89-verified]
#pragma unroll
    for (int j = 0; j < 4; ++j) {
      int o = ot * 16 + g * 4 + j;
      qp[(size_t)o * HW_] =
          (unsigned)f2bf(accn[j] * inv) | ((unsigned)f2bf(accd[j] * inv) << 16);
    }
  }
}

// ---- k3: depthwise 5x5 conv on P,Q + final ratios -> FP32 outputs ----
// v2: stage loads uint4-aligned 40-col window (whole-vector boundary mask),
//     float4 LDS writes; stage goes 5.06 scalar iters -> 1.4 vector iters.
__global__ void __launch_bounds__(256) k3_conv(const unsigned* __restrict__ PQ,
                                               const float* __restrict__ sw,
                                               const float* __restrict__ sums,
                                               float* __restrict__ out0,
                                               float* __restrict__ out1) {
  int t = blockIdx.x;
  int tile = t % 36;
  int chb = t / 36;  // b*128+ch
  int ch = chb & 127;
  int th0 = (tile / 6) * 32, tw0 = (tile % 6) * 32;
  __shared__ float Pt[1440], Qt[1440];  // 36 rows x 40 cols (cols gx tw0-4..tw0+35)
  const unsigned* src = PQ + (size_t)chb * HW_;
  int tid = threadIdx.x;
  for (int idx = tid; idx < 360; idx += 256) {  // 36 rows x 10 uint4
    int ly = idx / 10, q = idx - ly * 10;
    int gy = th0 + ly - 2;
    int gx = tw0 - 4 + q * 4;  // tw0%32==0 -> gx%4==0 -> 16B-aligned
    uint4 v = make_uint4(0, 0, 0, 0);
    if (gy >= 0 && gy < H_ && gx >= 0 && gx < W_)  // uint4 fully in or fully out
      v = *reinterpret_cast<const uint4*>(src + gy * W_ + gx);
    float4 pv4, qv4;
    pv4.x = bflo(v.x); pv4.y = bflo(v.y); pv4.z = bflo(v.z); pv4.w = bflo(v.w);
    qv4.x = bfhi(v.x); qv4.y = bfhi(v.y); qv4.z = bfhi(v.z); qv4.w = bfhi(v.w);
    *reinterpret_cast<float4*>(&Pt[ly * 40 + q * 4]) = pv4;
    *reinterpret_cast<float4*>(&Qt[ly * 40 + q * 4]) = qv4;
  }
  __syncthreads();
  float wr[25];
#pragma unroll
  for (int k = 0; k < 25; ++k) wr[k] = sw[ch * 25 + k];
  float isw = 1.0f / (sums[1] + EPS);
  int x = tid & 31, yg = tid >> 5;  // 32 cols x 8 row-groups (4 rows each)
  float an[4] = {0, 0, 0, 0}, ad[4] = {0, 0, 0, 0};
#pragma unroll
  for (int rr = 0; rr < 8; ++rr) {
    int Lr = yg * 4 + rr;
    float pv[5], qv[5];
#pragma unroll
    for (int c5 = 0; c5 < 5; ++c5) {
      pv[c5] = Pt[Lr * 40 + x + 2 + c5];  // pixel col x -> LDS col x+4; taps -2..+2
      qv[c5] = Qt[Lr * 40 + x + 2 + c5];
    }
#pragma unroll
    for (int k = 0; k < 4; ++k) {
      int ky = rr - k;
      if (ky >= 0 && ky <= 4) {
#pragma unroll
        for (int c5 = 0; c5 < 5; ++c5) {
          an[k] += pv[c5] * wr[ky * 5 + c5];
          ad[k] += qv[c5] * wr[ky * 5 + c5];
        }
      }
    }
  }
#pragma unroll
  for (int k = 0; k < 4; ++k) {
    int hh = th0 + yg * 4 + k;
    int oi = chb * HW_ + hh * W_ + tw0 + x;
    out0[oi] = an[k] / (ad[k] + EPS);
    out1[oi] = ad[k] * isw;
  }
}

extern "C" void kernel_launch(void* const* d_in, const int* in_sizes, int n_in,
                              void* d_out, int out_size, void* d_ws, size_t ws_size,
                              hipStream_t stream) {
  const float* d = (const float*)d_in[0];
  const float* cd = (const float*)d_in[1];
  const float* e = (const float*)d_in[2];
  const float* ce = (const float*)d_in[3];
  const float* wprop = (const float*)d_in[4];
  const float* wsd = (const float*)d_in[5];
  const float* cw = (const float*)d_in[6];
  const float* sw = (const float*)d_in[7];

  // ws layout (75.6 MB): sums(64 f32) | AWhi(16384 bf16) | AWlo(16384 bf16) | PQ(18874368 u32)
  // XY (bf16x2, 75.5 MB) staged in UPPER HALF of d_out; k2 consumes it before k3 writes.
  float* wsf = (float*)d_ws;
  float* sums = wsf;
  unsigned short* AWhi = (unsigned short*)(wsf + 64);
  unsigned short* AWlo = AWhi + 16384;
  unsigned* PQ = (unsigned*)(wsf + 64 + 16384);
  float* out0 = (float*)d_out;
  float* out1 = out0 + OUTELEMS;
  unsigned* XY = (unsigned*)(out0 + OUTELEMS);

  hipLaunchKernelGGL(k0_prep, dim3(65), dim3(256), 0, stream, cw, sw, AWhi, AWlo, sums);
  hipLaunchKernelGGL(k1_stage1, dim3(36, 128), dim3(256), 0, stream, d, cd, e, ce,
                     wprop, wsd, XY);
  hipLaunchKernelGGL(k2_mix, dim3(2304), dim3(256), 0, stream, XY, AWhi, AWlo, sums, PQ);
  hipLaunchKernelGGL(k3_conv, dim3(18432), dim3(256), 0, stream, PQ, sw, sums, out0,
                     out1);
}